// Round 1
// baseline (429.502 us; speedup 1.0000x reference)
//
#include <hip/hip_runtime.h>
#include <math.h>

static constexpr int E = 100000;   // edges (segments)
static constexpr int M = 1000000;  // edge-edge pairs

// ---------------- workspace layout (bytes) ----------------
#define O_FLAG   0                  // 1 int
#define O_WEFF   1024               // 128*8 f32 = 4096 B
#define O_BKEFF  5120               // 8 f32
#define O_COUNTS 8192               // E ints      = 400000 B
#define O_OFFS   408576             // E+1 ints    = 400004 B
#define O_CURS   808704             // E ints      = 400000 B
#define O_BSUM   1208832            // 391 ints
#define O_BSUM2  1210880            // 512 ints
#define O_CSR    1213440            // M ints      = 4000000 B
#define O_KS     5213696            // E*8 f32     = 3200000 B
#define O_VH     8519680            // E*128 f32   = 51200000 B
#define WS_NEEDED (O_VH + (size_t)E * 128 * 4)

// Detect whether edge_edge_index arrived as int64 (reference dtype) or int32.
// For int64 little-endian with values < 2^31, every odd int32 word is 0.
__global__ void k_detect(const int* __restrict__ idx32, int* __restrict__ flag) {
    if (blockIdx.x == 0 && threadIdx.x == 0) {
        int z = 0;
        for (int i = 0; i < 64; i++) z += (idx32[2 * i + 1] == 0) ? 1 : 0;
        *flag = (z == 64) ? 1 : 0;
    }
}

// Fold Aw into Wk:  weff[k][h] = sum_d Wk[k][h*16+d] * Aw[d][h];  bkeff likewise.
__global__ void k_weff(const float* __restrict__ Wk, const float* __restrict__ bk,
                       const float* __restrict__ Aw, float* __restrict__ weff,
                       float* __restrict__ bkeff) {
    int i = threadIdx.x;  // 0..127
    for (int h = 0; h < 8; h++) {
        float s = 0.f;
        for (int d = 0; d < 16; d++) s += Wk[i * 128 + h * 16 + d] * Aw[d * 8 + h];
        weff[i * 8 + h] = s;
    }
    if (i < 8) {
        float s = 0.f;
        for (int d = 0; d < 16; d++) s += bk[i * 16 + d] * Aw[d * 8 + i];
        bkeff[i] = s;
    }
}

__global__ void k_zero(int* __restrict__ counts, int* __restrict__ curs) {
    int i = blockIdx.x * blockDim.x + threadIdx.x;
    if (i < E) { counts[i] = 0; curs[i] = 0; }
}

__device__ __forceinline__ void load_pair(const void* idx, int flag, int m,
                                          int& s, int& d) {
    if (flag) {
        const long long* p = (const long long*)idx;
        s = (int)p[m];
        d = (int)p[M + m];
    } else {
        const int* p = (const int*)idx;
        s = p[m];
        d = p[M + m];
    }
}

__global__ void k_count(const void* __restrict__ idx, const int* __restrict__ flagp,
                        int* __restrict__ counts) {
    int m = blockIdx.x * blockDim.x + threadIdx.x;
    if (m >= M) return;
    int flag = *flagp;
    int s, d;
    load_pair(idx, flag, m, s, d);
    atomicAdd(&counts[d], 1);
}

// Per-block exclusive scan (256 elements), block totals to bsum.
__global__ void k_scanA(const int* __restrict__ counts, int* __restrict__ offs,
                        int* __restrict__ bsum) {
    __shared__ int sm[256];
    int tid = threadIdx.x;
    int i = blockIdx.x * 256 + tid;
    int v = (i < E) ? counts[i] : 0;
    sm[tid] = v;
    __syncthreads();
    for (int off = 1; off < 256; off <<= 1) {
        int add = (tid >= off) ? sm[tid - off] : 0;
        __syncthreads();
        sm[tid] += add;
        __syncthreads();
    }
    if (i < E) offs[i] = sm[tid] - v;
    if (tid == 255) bsum[blockIdx.x] = sm[255];
}

__global__ void k_scanB(const int* __restrict__ bsum, int* __restrict__ bsum2, int nb) {
    __shared__ int sm[512];
    int tid = threadIdx.x;
    int v = (tid < nb) ? bsum[tid] : 0;
    sm[tid] = v;
    __syncthreads();
    for (int off = 1; off < 512; off <<= 1) {
        int add = (tid >= off) ? sm[tid - off] : 0;
        __syncthreads();
        sm[tid] += add;
        __syncthreads();
    }
    bsum2[tid] = sm[tid] - v;  // exclusive
}

__global__ void k_scanC(int* __restrict__ offs, const int* __restrict__ bsum2) {
    int i = blockIdx.x * blockDim.x + threadIdx.x;
    if (i < E) offs[i] += bsum2[i >> 8];
    if (i == 0) offs[E] = M;
}

__global__ void k_fill(const void* __restrict__ idx, const int* __restrict__ flagp,
                       const int* __restrict__ offs, int* __restrict__ curs,
                       int* __restrict__ csr) {
    int m = blockIdx.x * blockDim.x + threadIdx.x;
    if (m >= M) return;
    int flag = *flagp;
    int s, d;
    load_pair(idx, flag, m, s, d);
    int pos = atomicAdd(&curs[d], 1);
    csr[offs[d] + pos] = s;
}

// Fused projection: Vh = A @ Wv + bv  (E x 128), ks = A @ weff + bkeff (E x 8).
// Block = 256 threads handles 16 rows. Wv (64 KiB) + A-tile (8 KiB) + weff (4 KiB) in LDS.
__global__ __launch_bounds__(256) void k_proj(
    const float* __restrict__ A, const float* __restrict__ Wv,
    const float* __restrict__ bv, const float* __restrict__ weff,
    const float* __restrict__ bkeff, float* __restrict__ Vh,
    float* __restrict__ ksb) {
    __shared__ float w_lds[128 * 128];
    __shared__ float a_lds[16][128];
    __shared__ float we_lds[128 * 8];
    int t = threadIdx.x;

    const float4* wv4 = (const float4*)Wv;
    float4* wl4 = (float4*)w_lds;
#pragma unroll
    for (int i = 0; i < 16; i++) wl4[t + i * 256] = wv4[t + i * 256];
    ((float4*)we_lds)[t] = ((const float4*)weff)[t];

    size_t rowbase = (size_t)blockIdx.x * 16;
    const float4* a4 = (const float4*)(A + rowbase * 128);
    float4* al4 = (float4*)(&a_lds[0][0]);
    al4[t] = a4[t];
    al4[t + 256] = a4[t + 256];
    __syncthreads();

    int c0 = (t & 31) * 4;
    int r0 = (t >> 5) * 2;
    float4 acc0 = make_float4(0.f, 0.f, 0.f, 0.f);
    float4 acc1 = make_float4(0.f, 0.f, 0.f, 0.f);
#pragma unroll 4
    for (int k = 0; k < 128; k++) {
        float4 w = *(const float4*)&w_lds[k * 128 + c0];
        float a0 = a_lds[r0][k];
        float a1 = a_lds[r0 + 1][k];
        acc0.x += w.x * a0; acc0.y += w.y * a0; acc0.z += w.z * a0; acc0.w += w.w * a0;
        acc1.x += w.x * a1; acc1.y += w.y * a1; acc1.z += w.z * a1; acc1.w += w.w * a1;
    }
    float4 bb = *(const float4*)(bv + c0);
    acc0.x += bb.x; acc0.y += bb.y; acc0.z += bb.z; acc0.w += bb.w;
    acc1.x += bb.x; acc1.y += bb.y; acc1.z += bb.z; acc1.w += bb.w;
    *(float4*)&Vh[(rowbase + r0) * 128 + c0] = acc0;
    *(float4*)&Vh[(rowbase + r0 + 1) * 128 + c0] = acc1;

    if (t < 128) {
        int r = t >> 3, h = t & 7;
        float s = bkeff[h];
#pragma unroll 8
        for (int k = 0; k < 128; k++) s += a_lds[r][k] * we_lds[k * 8 + h];
        ksb[(rowbase + r) * 8 + h] = s;
    }
}

// One wave per destination segment: softmax over ks[src], weighted gather of Vh[src].
// Lane owns output floats [2*lane, 2*lane+1] of the 128-float row -> head h = lane>>3.
__global__ __launch_bounds__(256) void k_seg(
    const float* __restrict__ ksb, const float* __restrict__ Vh,
    const int* __restrict__ offs, const int* __restrict__ csr,
    float* __restrict__ out) {
    int lane = threadIdx.x & 63;
    int seg = blockIdx.x * 4 + (threadIdx.x >> 6);
    if (seg >= E) return;
    int beg = offs[seg];
    int n = offs[seg + 1] - beg;
    int h = lane >> 3;
    float2 acc = make_float2(0.f, 0.f);

    if (n > 0) {
        float kk[8];
        int my_src = 0;
        bool have = lane < n;
        if (have) {
            my_src = csr[beg + lane];
            const float4* kp = (const float4*)(ksb + (size_t)my_src * 8);
            float4 k0 = kp[0], k1 = kp[1];
            kk[0] = k0.x; kk[1] = k0.y; kk[2] = k0.z; kk[3] = k0.w;
            kk[4] = k1.x; kk[5] = k1.y; kk[6] = k1.z; kk[7] = k1.w;
        } else {
#pragma unroll
            for (int j = 0; j < 8; j++) kk[j] = -INFINITY;
        }
        float mx[8];
#pragma unroll
        for (int j = 0; j < 8; j++) mx[j] = kk[j];
        for (int i = lane + 64; i < n; i += 64) {   // rare: n > 64
            int s = csr[beg + i];
            const float4* kp = (const float4*)(ksb + (size_t)s * 8);
            float4 k0 = kp[0], k1 = kp[1];
            mx[0] = fmaxf(mx[0], k0.x); mx[1] = fmaxf(mx[1], k0.y);
            mx[2] = fmaxf(mx[2], k0.z); mx[3] = fmaxf(mx[3], k0.w);
            mx[4] = fmaxf(mx[4], k1.x); mx[5] = fmaxf(mx[5], k1.y);
            mx[6] = fmaxf(mx[6], k1.z); mx[7] = fmaxf(mx[7], k1.w);
        }
#pragma unroll
        for (int off = 32; off >= 1; off >>= 1)
#pragma unroll
            for (int j = 0; j < 8; j++)
                mx[j] = fmaxf(mx[j], __shfl_xor(mx[j], off, 64));

        float sm[8];
#pragma unroll
        for (int j = 0; j < 8; j++) sm[j] = have ? __expf(kk[j] - mx[j]) : 0.f;
        for (int i = lane + 64; i < n; i += 64) {   // rare: n > 64
            int s = csr[beg + i];
            const float4* kp = (const float4*)(ksb + (size_t)s * 8);
            float4 k0 = kp[0], k1 = kp[1];
            sm[0] += __expf(k0.x - mx[0]); sm[1] += __expf(k0.y - mx[1]);
            sm[2] += __expf(k0.z - mx[2]); sm[3] += __expf(k0.w - mx[3]);
            sm[4] += __expf(k1.x - mx[4]); sm[5] += __expf(k1.y - mx[5]);
            sm[6] += __expf(k1.z - mx[6]); sm[7] += __expf(k1.w - mx[7]);
        }
#pragma unroll
        for (int off = 32; off >= 1; off >>= 1)
#pragma unroll
            for (int j = 0; j < 8; j++) sm[j] += __shfl_xor(sm[j], off, 64);

        // select this lane's head values (7 cndmasks each, no LDS round-trip)
        float mxh = mx[0], dh = sm[0];
#pragma unroll
        for (int j = 1; j < 8; j++)
            if (h == j) { mxh = mx[j]; dh = sm[j]; }
        float inv = 1.0f / (dh + 1e-16f);

        for (int i = 0; i < n; i++) {
            int s = (i < 64) ? __shfl(my_src, i, 64) : csr[beg + i];
            float kv = ksb[(size_t)s * 8 + h];
            float w = __expf(kv - mxh) * inv;
            float2 v = ((const float2*)(Vh + (size_t)s * 128))[lane];
            acc.x += v.x * w;
            acc.y += v.y * w;
        }
    }
    ((float2*)(out + (size_t)seg * 128))[lane] = acc;
}

extern "C" void kernel_launch(void* const* d_in, const int* in_sizes, int n_in,
                              void* d_out, int out_size, void* d_ws, size_t ws_size,
                              hipStream_t stream) {
    const float* edge_attr = (const float*)d_in[0];
    const void*  eei       = d_in[1];
    // d_in[2] = Wq, d_in[3] = bq  -- dead: Q cancels in the segment softmax
    const float* Wk = (const float*)d_in[4];
    const float* bk = (const float*)d_in[5];
    const float* Wv = (const float*)d_in[6];
    const float* bv = (const float*)d_in[7];
    const float* Aw = (const float*)d_in[8];
    float* out = (float*)d_out;

    if (ws_size < WS_NEEDED) return;  // will fail validation visibly

    char* ws = (char*)d_ws;
    int*   flag   = (int*)(ws + O_FLAG);
    float* weff   = (float*)(ws + O_WEFF);
    float* bkeff  = (float*)(ws + O_BKEFF);
    int*   counts = (int*)(ws + O_COUNTS);
    int*   offs   = (int*)(ws + O_OFFS);
    int*   curs   = (int*)(ws + O_CURS);
    int*   bsum   = (int*)(ws + O_BSUM);
    int*   bsum2  = (int*)(ws + O_BSUM2);
    int*   csr    = (int*)(ws + O_CSR);
    float* ksb    = (float*)(ws + O_KS);
    float* Vh     = (float*)(ws + O_VH);

    const int nbE = (E + 255) / 256;       // 391
    const int nbM = (M + 255) / 256;       // 3907

    k_detect<<<1, 64, 0, stream>>>((const int*)eei, flag);
    k_weff<<<1, 128, 0, stream>>>(Wk, bk, Aw, weff, bkeff);
    k_zero<<<nbE, 256, 0, stream>>>(counts, curs);
    k_count<<<nbM, 256, 0, stream>>>(eei, flag, counts);
    k_scanA<<<nbE, 256, 0, stream>>>(counts, offs, bsum);
    k_scanB<<<1, 512, 0, stream>>>(bsum, bsum2, nbE);
    k_scanC<<<nbE, 256, 0, stream>>>(offs, bsum2);
    k_fill<<<nbM, 256, 0, stream>>>(eei, flag, offs, curs, csr);
    k_proj<<<E / 16, 256, 0, stream>>>(edge_attr, Wv, bv, weff, bkeff, Vh, ksb);
    k_seg<<<(E + 3) / 4, 256, 0, stream>>>(ksb, Vh, offs, csr, out);
}

// Round 2
// 348.523 us; speedup vs baseline: 1.2323x; 1.2323x over previous
//
#include <hip/hip_runtime.h>
#include <math.h>

static constexpr int E = 100000;   // edges (segments)
static constexpr int M = 1000000;  // edge-edge pairs

// ---------------- workspace layout (bytes) ----------------
#define O_FLAG   0                  // 1 int
#define O_WEFF   512                // 128*8 f32 = 4096 B
#define O_BKEFF  4608               // 8 f32
#define O_BSWZ   5120               // 32 frags * 64 lanes * 8 bf16 = 32768 B
#define O_COUNTS 38400              // E ints   = 400000 B
#define O_OFFS   438784             // E+1 ints = 400004 B
#define O_CURS   839168             // E ints   = 400000 B
#define O_BSUM   1239552            // 391 ints
#define O_BSUM2  1241600            // 512 ints
#define O_CSR    1243648            // M ints   = 4000000 B
#define O_KS     5243904            // E*8 f32  = 3200000 B
#define O_VH     8444416            // E*128 bf16 = 25600000 B
#define WS_NEEDED (O_VH + (size_t)E * 128 * 2)

typedef float f32x4 __attribute__((ext_vector_type(4)));
typedef short s16x8 __attribute__((ext_vector_type(8)));

__device__ __forceinline__ unsigned short f2bf(float f) {
    unsigned u = __float_as_uint(f);
    u += 0x7fffu + ((u >> 16) & 1u);   // round-to-nearest-even
    return (unsigned short)(u >> 16);
}
__device__ __forceinline__ float bflo(unsigned u) { return __uint_as_float(u << 16); }
__device__ __forceinline__ float bfhi(unsigned u) { return __uint_as_float(u & 0xffff0000u); }

// Fused prep: zero counts/curs | fold Aw into Wk (weff) | int64-vs-int32 detect |
// pre-swizzle Wv into MFMA B-fragment order as bf16 (Bswz).
__global__ void k_prep(const float* __restrict__ Wk, const float* __restrict__ bk,
                       const float* __restrict__ Aw, const float* __restrict__ Wv,
                       const int* __restrict__ idx32, int* __restrict__ counts,
                       int* __restrict__ curs, int* __restrict__ flag,
                       float* __restrict__ weff, float* __restrict__ bkeff,
                       unsigned short* __restrict__ Bswz, int nbE) {
    int bid = blockIdx.x, t = threadIdx.x;
    if (bid < nbE) {
        int i = bid * 256 + t;
        if (i < E) { counts[i] = 0; curs[i] = 0; }
        return;
    }
    if (bid == nbE) {  // weff[k][h] = sum_d Wk[k][h*16+d] * Aw[d][h]
        if (t < 128) {
            for (int h = 0; h < 8; h++) {
                float s = 0.f;
                for (int d = 0; d < 16; d++) s += Wk[t * 128 + h * 16 + d] * Aw[d * 8 + h];
                weff[t * 8 + h] = s;
            }
            if (t < 8) {
                float s = 0.f;
                for (int d = 0; d < 16; d++) s += bk[t * 16 + d] * Aw[d * 8 + t];
                bkeff[t] = s;
            }
        }
        return;
    }
    if (bid == nbE + 1) {  // dtype detect: int64 little-endian -> odd words all 0
        if (t == 0) {
            int z = 0;
            for (int i = 0; i < 64; i++) z += (idx32[2 * i + 1] == 0) ? 1 : 0;
            *flag = (z == 64) ? 1 : 0;
        }
        return;
    }
    // B-swizzle: frag f=c*8+tt (c=k-chunk, tt=col-tile); value = Wv[k][n],
    // k = c*32+(lane>>4)*8+j, n = tt*16+(lane&15)  (B-operand layout, 16x16x32)
    int p = (bid - (nbE + 2)) * 256 + t;     // 0..2047 = f*64+lane
    int f = p >> 6, lane = p & 63;
    int c = f >> 3, tt = f & 7;
    int quad = lane >> 4, nn = lane & 15;
#pragma unroll
    for (int j = 0; j < 8; j++) {
        int k = c * 32 + quad * 8 + j;
        Bswz[p * 8 + j] = f2bf(Wv[k * 128 + tt * 16 + nn]);
    }
}

__global__ void k_count(const void* __restrict__ idx, const int* __restrict__ flagp,
                        int* __restrict__ counts) {
    int m = blockIdx.x * blockDim.x + threadIdx.x;
    if (m >= M) return;
    int d = (*flagp) ? (int)((const long long*)idx)[M + m] : ((const int*)idx)[M + m];
    atomicAdd(&counts[d], 1);
}

__global__ void k_scanA(const int* __restrict__ counts, int* __restrict__ offs,
                        int* __restrict__ bsum) {
    __shared__ int sm[256];
    int tid = threadIdx.x;
    int i = blockIdx.x * 256 + tid;
    int v = (i < E) ? counts[i] : 0;
    sm[tid] = v;
    __syncthreads();
    for (int off = 1; off < 256; off <<= 1) {
        int add = (tid >= off) ? sm[tid - off] : 0;
        __syncthreads();
        sm[tid] += add;
        __syncthreads();
    }
    if (i < E) offs[i] = sm[tid] - v;
    if (tid == 255) bsum[blockIdx.x] = sm[255];
}

__global__ void k_scanB(const int* __restrict__ bsum, int* __restrict__ bsum2, int nb) {
    __shared__ int sm[512];
    int tid = threadIdx.x;
    int v = (tid < nb) ? bsum[tid] : 0;
    sm[tid] = v;
    __syncthreads();
    for (int off = 1; off < 512; off <<= 1) {
        int add = (tid >= off) ? sm[tid - off] : 0;
        __syncthreads();
        sm[tid] += add;
        __syncthreads();
    }
    bsum2[tid] = sm[tid] - v;  // exclusive
}

__global__ void k_scanC(int* __restrict__ offs, const int* __restrict__ bsum2) {
    int i = blockIdx.x * blockDim.x + threadIdx.x;
    if (i < E) offs[i] += bsum2[i >> 8];
    if (i == 0) offs[E] = M;
}

__global__ void k_fill(const void* __restrict__ idx, const int* __restrict__ flagp,
                       const int* __restrict__ offs, int* __restrict__ curs,
                       int* __restrict__ csr) {
    int m = blockIdx.x * blockDim.x + threadIdx.x;
    if (m >= M) return;
    int s, d;
    if (*flagp) {
        const long long* p = (const long long*)idx;
        s = (int)p[m]; d = (int)p[M + m];
    } else {
        const int* p = (const int*)idx;
        s = p[m]; d = p[M + m];
    }
    int pos = atomicAdd(&curs[d], 1);
    csr[offs[d] + pos] = s;
}

// ks = A @ weff + bkeff  (E x 8).  Wave handles 4 rows; 16 lanes per row,
// each lane covers 8 consecutive k; partials reduced over the 16-lane group.
__global__ __launch_bounds__(256) void k_ks(
    const float* __restrict__ A, const float* __restrict__ weff,
    const float* __restrict__ bkeff, float* __restrict__ ksb) {
    __shared__ float we[1024];
    int t = threadIdx.x;
    ((float4*)we)[t] = ((const float4*)weff)[t & 255];
    __syncthreads();
    int lane = t & 63, w = t >> 6;
    int row = blockIdx.x * 16 + w * 4 + (lane >> 4);   // grid 6250 * 16 = E exactly
    int k0 = (lane & 15) * 8;
    const float4* ap = (const float4*)(A + (size_t)row * 128 + k0);
    float4 a0 = ap[0], a1 = ap[1];
    float a[8] = {a0.x, a0.y, a0.z, a0.w, a1.x, a1.y, a1.z, a1.w};
    float p[8];
#pragma unroll
    for (int h = 0; h < 8; h++) p[h] = 0.f;
#pragma unroll
    for (int j = 0; j < 8; j++)
#pragma unroll
        for (int h = 0; h < 8; h++) p[h] += a[j] * we[(k0 + j) * 8 + h];
#pragma unroll
    for (int off = 1; off <= 8; off <<= 1)
#pragma unroll
        for (int h = 0; h < 8; h++) p[h] += __shfl_xor(p[h], off, 64);
    if ((lane & 15) == 0) {
        float4* op = (float4*)(ksb + (size_t)row * 8);
        op[0] = make_float4(p[0] + bkeff[0], p[1] + bkeff[1], p[2] + bkeff[2], p[3] + bkeff[3]);
        op[1] = make_float4(p[4] + bkeff[4], p[5] + bkeff[5], p[6] + bkeff[6], p[7] + bkeff[7]);
    }
}

// Vh = bf16(A @ Wv + bv) via MFMA 16x16x32 bf16. Wave = 16 rows x 128 cols.
// A frags straight from global (fp32 -> bf16); B frags pre-swizzled (Bswz).
__global__ __launch_bounds__(256) void k_proj(
    const float* __restrict__ A, const short* __restrict__ Bswz,
    const float* __restrict__ bv, unsigned short* __restrict__ Vh) {
    int t = threadIdx.x;
    int lane = t & 63, wid = t >> 6;
    int rowbase = blockIdx.x * 64 + wid * 16;
    int quad = lane >> 4, nn = lane & 15;
    int m = rowbase + nn;
    int mc = (m < E) ? m : (E - 1);

    f32x4 acc[8];
#pragma unroll
    for (int tt = 0; tt < 8; tt++) acc[tt] = (f32x4){0.f, 0.f, 0.f, 0.f};

#pragma unroll
    for (int c = 0; c < 4; c++) {
        const float4* ap = (const float4*)(A + (size_t)mc * 128 + c * 32 + quad * 8);
        float4 f0 = ap[0], f1 = ap[1];
        s16x8 afrag;
        afrag[0] = (short)f2bf(f0.x); afrag[1] = (short)f2bf(f0.y);
        afrag[2] = (short)f2bf(f0.z); afrag[3] = (short)f2bf(f0.w);
        afrag[4] = (short)f2bf(f1.x); afrag[5] = (short)f2bf(f1.y);
        afrag[6] = (short)f2bf(f1.z); afrag[7] = (short)f2bf(f1.w);
#pragma unroll
        for (int tt = 0; tt < 8; tt++) {
            s16x8 bfrag = *(const s16x8*)(Bswz + (((c * 8 + tt) * 64 + lane) << 3));
            acc[tt] = __builtin_amdgcn_mfma_f32_16x16x32_bf16(afrag, bfrag, acc[tt], 0, 0, 0);
        }
    }
    // D layout: row = quad*4 + reg, col = tt*16 + nn
#pragma unroll
    for (int tt = 0; tt < 8; tt++) {
        float bvc = bv[tt * 16 + nn];
#pragma unroll
        for (int r = 0; r < 4; r++) {
            int row = rowbase + quad * 4 + r;
            if (row < E)
                Vh[(size_t)row * 128 + tt * 16 + nn] = f2bf(acc[tt][r] + bvc);
        }
    }
}

// Half-wave (32 lanes) per destination segment. Lane sl owns output elements
// [4*sl, 4*sl+4) -> head h = sl>>2. bf16 Vh gather, fp32 accumulate.
__global__ __launch_bounds__(256) void k_seg(
    const float* __restrict__ ksb, const unsigned short* __restrict__ Vh,
    const int* __restrict__ offs, const int* __restrict__ csr,
    float* __restrict__ out) {
    int t = threadIdx.x;
    int lane = t & 63;
    int sl = lane & 31;
    int halfbase = lane & 32;          // 0 or 32
    int seg = blockIdx.x * 8 + (t >> 5);
    if (seg >= E) return;
    int beg = offs[seg];
    int n = offs[seg + 1] - beg;
    int h = sl >> 2;
    float4 acc = make_float4(0.f, 0.f, 0.f, 0.f);

    if (n > 0) {
        float kk[8];
        int my_src = 0;
        bool have = sl < n;
        if (have) {
            my_src = csr[beg + sl];
            const float4* kp = (const float4*)(ksb + (size_t)my_src * 8);
            float4 k0 = kp[0], k1 = kp[1];
            kk[0] = k0.x; kk[1] = k0.y; kk[2] = k0.z; kk[3] = k0.w;
            kk[4] = k1.x; kk[5] = k1.y; kk[6] = k1.z; kk[7] = k1.w;
        } else {
#pragma unroll
            for (int j = 0; j < 8; j++) kk[j] = -INFINITY;
        }
        float mx[8];
#pragma unroll
        for (int j = 0; j < 8; j++) mx[j] = kk[j];
        for (int i = sl + 32; i < n; i += 32) {      // rare: n > 32
            int s = csr[beg + i];
            const float4* kp = (const float4*)(ksb + (size_t)s * 8);
            float4 k0 = kp[0], k1 = kp[1];
            mx[0] = fmaxf(mx[0], k0.x); mx[1] = fmaxf(mx[1], k0.y);
            mx[2] = fmaxf(mx[2], k0.z); mx[3] = fmaxf(mx[3], k0.w);
            mx[4] = fmaxf(mx[4], k1.x); mx[5] = fmaxf(mx[5], k1.y);
            mx[6] = fmaxf(mx[6], k1.z); mx[7] = fmaxf(mx[7], k1.w);
        }
#pragma unroll
        for (int off = 16; off >= 1; off >>= 1)
#pragma unroll
            for (int j = 0; j < 8; j++)
                mx[j] = fmaxf(mx[j], __shfl_xor(mx[j], off, 64));

        float sm[8];
#pragma unroll
        for (int j = 0; j < 8; j++) sm[j] = have ? __expf(kk[j] - mx[j]) : 0.f;
        for (int i = sl + 32; i < n; i += 32) {      // rare: n > 32
            int s = csr[beg + i];
            const float4* kp = (const float4*)(ksb + (size_t)s * 8);
            float4 k0 = kp[0], k1 = kp[1];
            sm[0] += __expf(k0.x - mx[0]); sm[1] += __expf(k0.y - mx[1]);
            sm[2] += __expf(k0.z - mx[2]); sm[3] += __expf(k0.w - mx[3]);
            sm[4] += __expf(k1.x - mx[4]); sm[5] += __expf(k1.y - mx[5]);
            sm[6] += __expf(k1.z - mx[6]); sm[7] += __expf(k1.w - mx[7]);
        }
#pragma unroll
        for (int off = 16; off >= 1; off >>= 1)
#pragma unroll
            for (int j = 0; j < 8; j++) sm[j] += __shfl_xor(sm[j], off, 64);

        float mxh = mx[0], dh = sm[0];
#pragma unroll
        for (int j = 1; j < 8; j++)
            if (h == j) { mxh = mx[j]; dh = sm[j]; }
        float inv = 1.0f / (dh + 1e-16f);

        for (int i = 0; i < n; i++) {
            int s = (i < 32) ? __shfl(my_src, halfbase + i, 64) : csr[beg + i];
            float kv = ksb[(size_t)s * 8 + h];
            float w = __expf(kv - mxh) * inv;
            uint2 u = ((const uint2*)(Vh + (size_t)s * 128))[sl];
            acc.x += bflo(u.x) * w;
            acc.y += bfhi(u.x) * w;
            acc.z += bflo(u.y) * w;
            acc.w += bfhi(u.y) * w;
        }
    }
    ((float4*)(out + (size_t)seg * 128))[sl] = acc;
}

extern "C" void kernel_launch(void* const* d_in, const int* in_sizes, int n_in,
                              void* d_out, int out_size, void* d_ws, size_t ws_size,
                              hipStream_t stream) {
    const float* edge_attr = (const float*)d_in[0];
    const void*  eei       = d_in[1];
    // d_in[2] = Wq, d_in[3] = bq  -- dead: Q cancels in the segment softmax
    const float* Wk = (const float*)d_in[4];
    const float* bk = (const float*)d_in[5];
    const float* Wv = (const float*)d_in[6];
    const float* bv = (const float*)d_in[7];
    const float* Aw = (const float*)d_in[8];
    float* out = (float*)d_out;

    if (ws_size < WS_NEEDED) return;

    char* ws = (char*)d_ws;
    int*   flag   = (int*)(ws + O_FLAG);
    float* weff   = (float*)(ws + O_WEFF);
    float* bkeff  = (float*)(ws + O_BKEFF);
    unsigned short* Bswz = (unsigned short*)(ws + O_BSWZ);
    int*   counts = (int*)(ws + O_COUNTS);
    int*   offs   = (int*)(ws + O_OFFS);
    int*   curs   = (int*)(ws + O_CURS);
    int*   bsum   = (int*)(ws + O_BSUM);
    int*   bsum2  = (int*)(ws + O_BSUM2);
    int*   csr    = (int*)(ws + O_CSR);
    float* ksb    = (float*)(ws + O_KS);
    unsigned short* Vh = (unsigned short*)(ws + O_VH);

    const int nbE = (E + 255) / 256;       // 391
    const int nbM = (M + 255) / 256;       // 3907

    k_prep<<<nbE + 10, 256, 0, stream>>>(Wk, bk, Aw, Wv, (const int*)eei,
                                         counts, curs, flag, weff, bkeff, Bswz, nbE);
    k_count<<<nbM, 256, 0, stream>>>(eei, flag, counts);
    k_scanA<<<nbE, 256, 0, stream>>>(counts, offs, bsum);
    k_scanB<<<1, 512, 0, stream>>>(bsum, bsum2, nbE);
    k_scanC<<<nbE, 256, 0, stream>>>(offs, bsum2);
    k_fill<<<nbM, 256, 0, stream>>>(eei, flag, offs, curs, csr);
    k_ks<<<E / 16, 256, 0, stream>>>(edge_attr, weff, bkeff, ksb);
    k_proj<<<(E + 63) / 64, 256, 0, stream>>>(edge_attr, (const short*)Bswz, bv, Vh);
    k_seg<<<(E + 7) / 8, 256, 0, stream>>>(ksb, Vh, offs, csr, out);
}

// Round 3
// 267.191 us; speedup vs baseline: 1.6075x; 1.3044x over previous
//
#include <hip/hip_runtime.h>
#include <math.h>

static constexpr int E = 100000;   // edges (segments)
static constexpr int M = 1000000;  // edge-edge pairs

// ---------------- workspace layout (bytes) ----------------
#define O_FLAG   0                  // 1 int
#define O_WEFF   512                // 128*8 f32 = 4096 B
#define O_BKEFF  4608               // 8 f32
#define O_BSWZ   5120               // 32 frags * 64 lanes * 8 bf16 = 32768 B
#define O_COUNTS 38400              // E ints   = 400000 B
#define O_OFFS   438784             // E ints   = 400000 B
#define O_BSUM   838784             // 391 ints (pad to 2048)
#define O_BSUM2  840832             // 512 ints = 2048 B
#define O_POS    842880             // M ints   = 4000000 B
#define O_CSR    4842880            // M ints   = 4000000 B
#define O_KS     8842880            // E*8 f32  = 3200000 B
#define O_VH     12042880           // E*128 bf16 = 25600000 B
#define WS_NEEDED (O_VH + (size_t)E * 128 * 2)

typedef float f32x4 __attribute__((ext_vector_type(4)));
typedef short s16x8 __attribute__((ext_vector_type(8)));

__device__ __forceinline__ unsigned short f2bf(float f) {
    unsigned u = __float_as_uint(f);
    u += 0x7fffu + ((u >> 16) & 1u);   // round-to-nearest-even
    return (unsigned short)(u >> 16);
}
__device__ __forceinline__ float bflo(unsigned u) { return __uint_as_float(u << 16); }
__device__ __forceinline__ float bfhi(unsigned u) { return __uint_as_float(u & 0xffff0000u); }

// Fused prep: zero counts | fold Aw into Wk (weff/bkeff) | int64-vs-int32 detect |
// pre-swizzle Wv into MFMA B-fragment order as bf16 (Bswz).
__global__ void k_prep(const float* __restrict__ Wk, const float* __restrict__ bk,
                       const float* __restrict__ Aw, const float* __restrict__ Wv,
                       const int* __restrict__ idx32, int* __restrict__ counts,
                       int* __restrict__ flag, float* __restrict__ weff,
                       float* __restrict__ bkeff, unsigned short* __restrict__ Bswz,
                       int nbE) {
    int bid = blockIdx.x, t = threadIdx.x;
    if (bid < nbE) {
        int i = bid * 256 + t;
        if (i < E) counts[i] = 0;
        return;
    }
    if (bid == nbE) {  // weff[k][h] = sum_d Wk[k][h*16+d] * Aw[d][h]
        if (t < 128) {
            for (int h = 0; h < 8; h++) {
                float s = 0.f;
                for (int d = 0; d < 16; d++) s += Wk[t * 128 + h * 16 + d] * Aw[d * 8 + h];
                weff[t * 8 + h] = s;
            }
            if (t < 8) {
                float s = 0.f;
                for (int d = 0; d < 16; d++) s += bk[t * 16 + d] * Aw[d * 8 + t];
                bkeff[t] = s;
            }
        }
        return;
    }
    if (bid == nbE + 1) {  // dtype detect: int64 little-endian -> odd words all 0
        if (t == 0) {
            int z = 0;
            for (int i = 0; i < 64; i++) z += (idx32[2 * i + 1] == 0) ? 1 : 0;
            *flag = (z == 64) ? 1 : 0;
        }
        return;
    }
    // B-swizzle: frag f=c*8+tt; value = Wv[k][n], k=c*32+(lane>>4)*8+j, n=tt*16+(lane&15)
    int p = (bid - (nbE + 2)) * 256 + t;     // 0..2047 = f*64+lane
    int f = p >> 6, lane = p & 63;
    int c = f >> 3, tt = f & 7;
    int quad = lane >> 4, nn = lane & 15;
#pragma unroll
    for (int j = 0; j < 8; j++) {
        int k = c * 32 + quad * 8 + j;
        Bswz[p * 8 + j] = f2bf(Wv[k * 128 + tt * 16 + nn]);
    }
}

// One atomic pass: per-pair rank within its dst segment + final counts.
__global__ void k_count(const void* __restrict__ idx, const int* __restrict__ flagp,
                        int* __restrict__ counts, int* __restrict__ pos) {
    int m = blockIdx.x * blockDim.x + threadIdx.x;
    if (m >= M) return;
    int d = (*flagp) ? (int)((const long long*)idx)[M + m] : ((const int*)idx)[M + m];
    pos[m] = atomicAdd(&counts[d], 1);
}

// Per-block exclusive scan (256 elements), block totals to bsum.
__global__ void k_scanA(const int* __restrict__ counts, int* __restrict__ offs,
                        int* __restrict__ bsum) {
    __shared__ int sm[256];
    int tid = threadIdx.x;
    int i = blockIdx.x * 256 + tid;
    int v = (i < E) ? counts[i] : 0;
    sm[tid] = v;
    __syncthreads();
    for (int off = 1; off < 256; off <<= 1) {
        int add = (tid >= off) ? sm[tid - off] : 0;
        __syncthreads();
        sm[tid] += add;
        __syncthreads();
    }
    if (i < E) offs[i] = sm[tid] - v;
    if (tid == 255) bsum[blockIdx.x] = sm[255];
}

__global__ void k_scanB(const int* __restrict__ bsum, int* __restrict__ bsum2, int nb) {
    __shared__ int sm[512];
    int tid = threadIdx.x;
    int v = (tid < nb) ? bsum[tid] : 0;
    sm[tid] = v;
    __syncthreads();
    for (int off = 1; off < 512; off <<= 1) {
        int add = (tid >= off) ? sm[tid - off] : 0;
        __syncthreads();
        sm[tid] += add;
        __syncthreads();
    }
    bsum2[tid] = sm[tid] - v;  // exclusive
}

// Atomic-free fill: csr[offs[d]+bsum2[d>>8]+pos[m]] = s.
__global__ void k_fill(const void* __restrict__ idx, const int* __restrict__ flagp,
                       const int* __restrict__ offs, const int* __restrict__ bsum2,
                       const int* __restrict__ pos, int* __restrict__ csr) {
    int m = blockIdx.x * blockDim.x + threadIdx.x;
    if (m >= M) return;
    int s, d;
    if (*flagp) {
        const long long* p = (const long long*)idx;
        s = (int)p[m]; d = (int)p[M + m];
    } else {
        const int* p = (const int*)idx;
        s = p[m]; d = p[M + m];
    }
    csr[offs[d] + bsum2[d >> 8] + pos[m]] = s;
}

// Fused projection: Vh = bf16(A @ Wv + bv) via MFMA 16x16x32 bf16, and
// ks = A @ weff + bkeff in exact fp32 (weff in LDS, quad-reduced via shuffles).
__global__ __launch_bounds__(256) void k_proj(
    const float* __restrict__ A, const short* __restrict__ Bswz,
    const float* __restrict__ bv, const float* __restrict__ weff,
    const float* __restrict__ bkeff, unsigned short* __restrict__ Vh,
    float* __restrict__ ksb) {
    __shared__ float we[1024];
    int t = threadIdx.x;
    ((float4*)we)[t] = ((const float4*)weff)[t & 255];
    __syncthreads();

    int lane = t & 63, wid = t >> 6;
    int rowbase = blockIdx.x * 64 + wid * 16;
    int quad = lane >> 4, nn = lane & 15;
    int m = rowbase + nn;
    int mc = (m < E) ? m : (E - 1);

    f32x4 acc[8];
#pragma unroll
    for (int tt = 0; tt < 8; tt++) acc[tt] = (f32x4){0.f, 0.f, 0.f, 0.f};
    float p[8];
#pragma unroll
    for (int h = 0; h < 8; h++) p[h] = 0.f;

#pragma unroll
    for (int c = 0; c < 4; c++) {
        const float4* ap = (const float4*)(A + (size_t)mc * 128 + c * 32 + quad * 8);
        float4 f0 = ap[0], f1 = ap[1];
        float a[8] = {f0.x, f0.y, f0.z, f0.w, f1.x, f1.y, f1.z, f1.w};
        // fp32 ks partial over this lane's 32 columns
#pragma unroll
        for (int j = 0; j < 8; j++) {
            int k = c * 32 + quad * 8 + j;
            float4 w0 = *(const float4*)&we[k * 8];
            float4 w1 = *(const float4*)&we[k * 8 + 4];
            p[0] += a[j] * w0.x; p[1] += a[j] * w0.y;
            p[2] += a[j] * w0.z; p[3] += a[j] * w0.w;
            p[4] += a[j] * w1.x; p[5] += a[j] * w1.y;
            p[6] += a[j] * w1.z; p[7] += a[j] * w1.w;
        }
        s16x8 afrag;
#pragma unroll
        for (int j = 0; j < 8; j++) afrag[j] = (short)f2bf(a[j]);
#pragma unroll
        for (int tt = 0; tt < 8; tt++) {
            s16x8 bfrag = *(const s16x8*)(Bswz + (((c * 8 + tt) * 64 + lane) << 3));
            acc[tt] = __builtin_amdgcn_mfma_f32_16x16x32_bf16(afrag, bfrag, acc[tt], 0, 0, 0);
        }
    }
    // reduce ks partials across quads (lane = quad*16 + nn)
#pragma unroll
    for (int off = 16; off <= 32; off <<= 1)
#pragma unroll
        for (int h = 0; h < 8; h++) p[h] += __shfl_xor(p[h], off, 64);
    if (quad == 0 && m < E) {
        float4* op = (float4*)(ksb + (size_t)m * 8);
        op[0] = make_float4(p[0] + bkeff[0], p[1] + bkeff[1], p[2] + bkeff[2], p[3] + bkeff[3]);
        op[1] = make_float4(p[4] + bkeff[4], p[5] + bkeff[5], p[6] + bkeff[6], p[7] + bkeff[7]);
    }
    // D layout: row = quad*4 + reg, col = tt*16 + nn
#pragma unroll
    for (int tt = 0; tt < 8; tt++) {
        float bvc = bv[tt * 16 + nn];
#pragma unroll
        for (int r = 0; r < 4; r++) {
            int row = rowbase + quad * 4 + r;
            if (row < E)
                Vh[(size_t)row * 128 + tt * 16 + nn] = f2bf(acc[tt][r] + bvc);
        }
    }
}

// One lane per (segment, head): serial max pass, then fused Σw / Σw·V pass.
// 8 lanes per segment; Vh reads are 2x uint4 per lane = 256B contiguous per seg.
__global__ __launch_bounds__(256) void k_seg(
    const float* __restrict__ ksb, const unsigned short* __restrict__ Vh,
    const int* __restrict__ offs, const int* __restrict__ bsum2,
    const int* __restrict__ csr, float* __restrict__ out) {
    int t = threadIdx.x;
    int h = t & 7;
    int seg = blockIdx.x * 32 + (t >> 3);          // grid 3125*32 = E exactly
    int beg = offs[seg] + bsum2[seg >> 8];
    int end = (seg + 1 < E) ? (offs[seg + 1] + bsum2[(seg + 1) >> 8]) : M;
    int n = end - beg;
    const float* kb = ksb + h;

    float acc[16];
#pragma unroll
    for (int j = 0; j < 16; j++) acc[j] = 0.f;
    float l = 0.f;

    if (n > 0) {
        float mx = -INFINITY;
        for (int i = 0; i < n; i++) {
            int s = csr[beg + i];
            mx = fmaxf(mx, kb[(size_t)s * 8]);
        }
        for (int i = 0; i < n; i++) {
            int s = csr[beg + i];
            float w = __expf(kb[(size_t)s * 8] - mx);
            l += w;
            const uint4* vp = (const uint4*)(Vh + (size_t)s * 128 + h * 16);
            uint4 v0 = vp[0], v1 = vp[1];
            acc[0]  += bflo(v0.x) * w; acc[1]  += bfhi(v0.x) * w;
            acc[2]  += bflo(v0.y) * w; acc[3]  += bfhi(v0.y) * w;
            acc[4]  += bflo(v0.z) * w; acc[5]  += bfhi(v0.z) * w;
            acc[6]  += bflo(v0.w) * w; acc[7]  += bfhi(v0.w) * w;
            acc[8]  += bflo(v1.x) * w; acc[9]  += bfhi(v1.x) * w;
            acc[10] += bflo(v1.y) * w; acc[11] += bfhi(v1.y) * w;
            acc[12] += bflo(v1.z) * w; acc[13] += bfhi(v1.z) * w;
            acc[14] += bflo(v1.w) * w; acc[15] += bfhi(v1.w) * w;
        }
    }
    float inv = 1.0f / (l + 1e-16f);
    float4* op = (float4*)(out + (size_t)seg * 128 + h * 16);
#pragma unroll
    for (int j = 0; j < 4; j++)
        op[j] = make_float4(acc[4 * j] * inv, acc[4 * j + 1] * inv,
                            acc[4 * j + 2] * inv, acc[4 * j + 3] * inv);
}

extern "C" void kernel_launch(void* const* d_in, const int* in_sizes, int n_in,
                              void* d_out, int out_size, void* d_ws, size_t ws_size,
                              hipStream_t stream) {
    const float* edge_attr = (const float*)d_in[0];
    const void*  eei       = d_in[1];
    // d_in[2] = Wq, d_in[3] = bq  -- dead: Q cancels in the segment softmax
    const float* Wk = (const float*)d_in[4];
    const float* bk = (const float*)d_in[5];
    const float* Wv = (const float*)d_in[6];
    const float* bv = (const float*)d_in[7];
    const float* Aw = (const float*)d_in[8];
    float* out = (float*)d_out;

    if (ws_size < WS_NEEDED) return;

    char* ws = (char*)d_ws;
    int*   flag   = (int*)(ws + O_FLAG);
    float* weff   = (float*)(ws + O_WEFF);
    float* bkeff  = (float*)(ws + O_BKEFF);
    unsigned short* Bswz = (unsigned short*)(ws + O_BSWZ);
    int*   counts = (int*)(ws + O_COUNTS);
    int*   offs   = (int*)(ws + O_OFFS);
    int*   bsum   = (int*)(ws + O_BSUM);
    int*   bsum2  = (int*)(ws + O_BSUM2);
    int*   pos    = (int*)(ws + O_POS);
    int*   csr    = (int*)(ws + O_CSR);
    float* ksb    = (float*)(ws + O_KS);
    unsigned short* Vh = (unsigned short*)(ws + O_VH);

    const int nbE = (E + 255) / 256;       // 391
    const int nbM = (M + 255) / 256;       // 3907

    k_prep<<<nbE + 10, 256, 0, stream>>>(Wk, bk, Aw, Wv, (const int*)eei,
                                         counts, flag, weff, bkeff, Bswz, nbE);
    k_count<<<nbM, 256, 0, stream>>>(eei, flag, counts, pos);
    k_scanA<<<nbE, 256, 0, stream>>>(counts, offs, bsum);
    k_scanB<<<1, 512, 0, stream>>>(bsum, bsum2, nbE);
    k_fill<<<nbM, 256, 0, stream>>>(eei, flag, offs, bsum2, pos, csr);
    k_proj<<<(E + 63) / 64, 256, 0, stream>>>(edge_attr, (const short*)Bswz, bv,
                                              weff, bkeff, Vh, ksb);
    k_seg<<<E / 32, 256, 0, stream>>>(ksb, Vh, offs, bsum2, csr, out);
}